// Round 8
// baseline (635.457 us; speedup 1.0000x reference)
//
#include <hip/hip_runtime.h>
#include <cstdint>
#include <cstddef>

#define B_     4
#define NPATCH 1024
#define LSEQ   1025
#define PDIM   768
#define DIM    512
#define OUTD   512
#define DIN    1024
#define DSTATE 16
#define DTRANK 32
#define KCONV  4
#define NBLK   2
#define MROWS  (B_*LSEQ)   // 4100
#define NSEG_SP 17

typedef unsigned short u16;
typedef __attribute__((ext_vector_type(8))) short bf16x8;
typedef __attribute__((ext_vector_type(4))) float f32x4;

__device__ __forceinline__ float sigmoidf_(float x){ return 1.f/(1.f+__expf(-x)); }
__device__ __forceinline__ float geluf_(float x){ return 0.5f*x*(1.f+erff(x*0.70710678118654752f)); }
__device__ __forceinline__ u16 f2bf(float x){
    uint32_t b = __float_as_uint(x);
    b += 0x7FFFu + ((b >> 16) & 1u);
    return (u16)(b >> 16);
}
__device__ __forceinline__ float bf2f(u16 v){ return __uint_as_float((uint32_t)v << 16); }
template<int CTRL>
__device__ __forceinline__ float dppmov(float x){
    return __int_as_float(__builtin_amdgcn_update_dpp(0, __float_as_int(x), CTRL, 0xF, 0xF, true));
}
__device__ __forceinline__ float red16(float p){
    p += dppmov<0xB1>(p);
    p += dppmov<0x4E>(p);
    p += dppmov<0x141>(p);
    p += dppmov<0x140>(p);
    return p;
}
__device__ __forceinline__ void gload16(const void* g, void* l){
    __builtin_amdgcn_global_load_lds((const __attribute__((address_space(1))) void*)g,
                                     (__attribute__((address_space(3))) void*)l, 16, 0, 0);
}
__device__ __forceinline__ float softplusf_(float v){
    return (v > 20.f) ? v : log1pf(__expf(v));
}

// =============== bf16 MFMA NT GEMM: C[M,N] = A[M,K]bf16 @ Wt[N,K]bf16^T ===============
template<int MF>
__global__ __launch_bounds__(256) void gemm_mfma(
    const u16* __restrict__ A, int lda,
    const u16* __restrict__ Wt,
    float* __restrict__ C, int ldc,
    int M, int N, int K,
    const float* __restrict__ bias,
    const float* __restrict__ addsrc,
    int act, u16* __restrict__ bf16out)
{
    __shared__ u16 lsA[MF*32*32];
    __shared__ u16 lsB[128*32];
    const int tid = threadIdx.x;
    const int wid = tid >> 6, lane = tid & 63;
    const int m0 = blockIdx.y * (MF*32), n0 = blockIdx.x * 128;
    const int wm = (wid>>1)*(MF*16), wn = (wid&1)*64;
    f32x4 acc[MF][4] = {};

    const char* Agp = (const char*)(A + (size_t)m0 * lda);
    const char* Bgp = (const char*)(Wt + (size_t)n0 * K);
    const int lrow = lane >> 2;
    const int lcb  = (((lane & 3) ^ ((lane >> 3) & 3))) * 16;
    const int rsw  = ((lane & 15) >> 1) & 3;
    const int acol = ((lane >> 4) ^ rsw) * 8;

    for (int k0 = 0; k0 < K; k0 += 32) {
        {
            int ra = wid*(MF*8) + lrow;
            gload16(Agp + (size_t)ra*(lda*2) + k0*2 + lcb, &lsA[(wid*(MF*8))*32]);
            if constexpr (MF == 4) {
                gload16(Agp + (size_t)(ra+16)*(lda*2) + k0*2 + lcb, &lsA[(wid*(MF*8)+16)*32]);
            }
        }
        {
            int rb = wid*32 + lrow;
            gload16(Bgp + (size_t)rb*(K*2) + k0*2 + lcb, &lsB[(wid*32)*32]);
            gload16(Bgp + (size_t)(rb+16)*(K*2) + k0*2 + lcb, &lsB[(wid*32+16)*32]);
        }
        __syncthreads();
        bf16x8 af[MF], bfr[4];
        #pragma unroll
        for (int i = 0; i < MF; ++i)
            af[i] = *(const bf16x8*)&lsA[(wm + i*16 + (lane&15))*32 + acol];
        #pragma unroll
        for (int j = 0; j < 4; ++j)
            bfr[j] = *(const bf16x8*)&lsB[(wn + j*16 + (lane&15))*32 + acol];
        #pragma unroll
        for (int i = 0; i < MF; ++i)
            #pragma unroll
            for (int j = 0; j < 4; ++j)
                acc[i][j] = __builtin_amdgcn_mfma_f32_16x16x32_bf16(af[i], bfr[j], acc[i][j], 0, 0, 0);
        __syncthreads();
    }
    #pragma unroll
    for (int i = 0; i < MF; ++i) {
        #pragma unroll
        for (int j = 0; j < 4; ++j) {
            int col = n0 + wn + j*16 + (lane & 15);
            float bv = bias ? bias[col] : 0.f;
            #pragma unroll
            for (int r = 0; r < 4; ++r) {
                int row = m0 + wm + i*16 + (lane>>4)*4 + r;
                if (row < M) {
                    float v = acc[i][j][r] + bv;
                    if (addsrc) v += addsrc[(size_t)row*ldc + col];
                    if (act == 1) v = softplusf_(v);
                    if (C) C[(size_t)row*ldc + col] = v;
                    if (bf16out) bf16out[(size_t)row*ldc + col] = f2bf(v);
                }
            }
        }
    }
}

// =============== xproj split-K f32 GEMM: P[kc][4100][64] partials ===============
__global__ __launch_bounds__(256) void xproj_gemm(
    const float* __restrict__ Au,
    const float* __restrict__ W,
    float* __restrict__ P)
{
    __shared__ float As[16][68];
    __shared__ float Bs[16][68];
    int tid = threadIdx.x;
    int tx = tid & 15, ty = tid >> 4;
    int m0 = blockIdx.x * 64;
    int kbase = blockIdx.y * 256;
    float acc[4][4] = {};
    for (int k0 = kbase; k0 < kbase + 256; k0 += 16) {
        {
            int r  = tid >> 2;
            int kq = (tid & 3) << 2;
            float4 va = make_float4(0.f,0.f,0.f,0.f);
            int gr = m0 + r;
            if (gr < MROWS) va = *reinterpret_cast<const float4*>(Au + (size_t)gr*DIN + k0 + kq);
            As[kq+0][r]=va.x; As[kq+1][r]=va.y; As[kq+2][r]=va.z; As[kq+3][r]=va.w;
        }
        {
            int kk = tid >> 4;
            int nq = (tid & 15) << 2;
            float4 vb = *reinterpret_cast<const float4*>(W + (size_t)(k0+kk)*64 + nq);
            Bs[kk][nq+0]=vb.x; Bs[kk][nq+1]=vb.y; Bs[kk][nq+2]=vb.z; Bs[kk][nq+3]=vb.w;
        }
        __syncthreads();
        #pragma unroll
        for (int k = 0; k < 16; ++k) {
            float a0=As[k][ty*4+0],a1=As[k][ty*4+1],a2=As[k][ty*4+2],a3=As[k][ty*4+3];
            float b0=Bs[k][tx*4+0],b1=Bs[k][tx*4+1],b2=Bs[k][tx*4+2],b3=Bs[k][tx*4+3];
            acc[0][0]=fmaf(a0,b0,acc[0][0]); acc[0][1]=fmaf(a0,b1,acc[0][1]);
            acc[0][2]=fmaf(a0,b2,acc[0][2]); acc[0][3]=fmaf(a0,b3,acc[0][3]);
            acc[1][0]=fmaf(a1,b0,acc[1][0]); acc[1][1]=fmaf(a1,b1,acc[1][1]);
            acc[1][2]=fmaf(a1,b2,acc[1][2]); acc[1][3]=fmaf(a1,b3,acc[1][3]);
            acc[2][0]=fmaf(a2,b0,acc[2][0]); acc[2][1]=fmaf(a2,b1,acc[2][1]);
            acc[2][2]=fmaf(a2,b2,acc[2][2]); acc[2][3]=fmaf(a2,b3,acc[2][3]);
            acc[3][0]=fmaf(a3,b0,acc[3][0]); acc[3][1]=fmaf(a3,b1,acc[3][1]);
            acc[3][2]=fmaf(a3,b2,acc[3][2]); acc[3][3]=fmaf(a3,b3,acc[3][3]);
        }
        __syncthreads();
    }
    float* Pp = P + (size_t)blockIdx.y * (MROWS*64);
    #pragma unroll
    for (int i = 0; i < 4; ++i) {
        int r = m0 + ty*4 + i;
        if (r >= MROWS) continue;
        #pragma unroll
        for (int j = 0; j < 4; ++j)
            Pp[(size_t)r*64 + tx*4 + j] = acc[i][j];
    }
}

__global__ __launch_bounds__(256) void xproj_reduce(
    const float* __restrict__ P, float* __restrict__ xdbl)
{
    int idx = blockIdx.x*256 + threadIdx.x;
    xdbl[idx] = P[idx] + P[MROWS*64 + idx] + P[2*MROWS*64 + idx] + P[3*MROWS*64 + idx];
}

// =============== prep: img cast + weight transpose-casts ===============
__device__ void tcast(const float* __restrict__ in, u16* __restrict__ outp,
                      int K, int N, int tix)
{
    __shared__ float tl[32][33];
    int ntn = N >> 5;
    int tk = tix / ntn, tn = tix - tk*ntn;
    int tid = threadIdx.x;
    int r = tid >> 3, c0 = (tid & 7) << 2;
    float4 v = *(const float4*)&in[(size_t)(tk*32 + r)*N + tn*32 + c0];
    tl[r][c0+0]=v.x; tl[r][c0+1]=v.y; tl[r][c0+2]=v.z; tl[r][c0+3]=v.w;
    __syncthreads();
    int nn = r, k0 = c0;
    uint32_t w0 = f2bf(tl[k0+0][nn]) | ((uint32_t)f2bf(tl[k0+1][nn]) << 16);
    uint32_t w1 = f2bf(tl[k0+2][nn]) | ((uint32_t)f2bf(tl[k0+3][nn]) << 16);
    uint2 o; o.x = w0; o.y = w1;
    *(uint2*)&outp[(size_t)(tn*32 + nn)*K + tk*32 + k0] = o;
}

__global__ __launch_bounds__(256) void prep_kernel(
    const float* __restrict__ img, const float* __restrict__ pW,
    const float* __restrict__ inW, const float* __restrict__ outW,
    const float* __restrict__ s1W, const float* __restrict__ s2W,
    u16* imgb, u16* pWt, u16* inWt, u16* outWt, u16* s1t, u16* s2t)
{
    int b = blockIdx.x;
    if (b < 3072) {
        int idx = b*1024 + threadIdx.x*4;
        float4 v = *(const float4*)&img[idx];
        uint2 o;
        o.x = f2bf(v.x) | ((uint32_t)f2bf(v.y) << 16);
        o.y = f2bf(v.z) | ((uint32_t)f2bf(v.w) << 16);
        *(uint2*)&imgb[idx] = o;
        return;
    }
    b -= 3072;
    if (b < 384)  { tcast(pW, pWt, 768, 512, b); return; }
    b -= 384;
    if (b < 2048) { int blk=b>>10, t=b&1023; tcast(inW + (size_t)blk*512*2048, inWt + (size_t)blk*1048576, 512, 2048, t); return; }
    b -= 2048;
    if (b < 1024) { int blk=b>>9, t=b&511; tcast(outW + (size_t)blk*1024*512, outWt + (size_t)blk*524288, 1024, 512, t); return; }
    b -= 1024;
    if (b < 256)  { tcast(s1W, s1t, 512, 512, b); return; }
    b -= 256;
    tcast(s2W, s2t, 512, 512, b);
}

// =============== assemble x = concat(cls, patches) + pos ===============
__global__ __launch_bounds__(256) void assemble_x(
    const float* __restrict__ tmp, const float* __restrict__ cls,
    const float* __restrict__ pos, float* __restrict__ x)
{
    int idx = blockIdx.x*256 + threadIdx.x;
    int d = idx & 511;
    int r = idx >> 9;
    int l = r % LSEQ;
    int b = r / LSEQ;
    float v = (l == 0) ? cls[d] : tmp[((size_t)(b*NPATCH + l-1))*DIM + d];
    x[idx] = v + pos[(size_t)l*DIM + d];
}

// =============== row LayerNorm (+gelu), 512 cols ===============
__global__ __launch_bounds__(256) void ln_act(
    const float* __restrict__ in, const float* __restrict__ gw, const float* __restrict__ gb,
    float* __restrict__ f32out, u16* __restrict__ bf16out, int act)
{
    int row = blockIdx.x;
    const float* p = in + (size_t)row * 512;
    int t = threadIdx.x;
    float v0 = p[t], v1 = p[t + 256];
    float s = v0 + v1, q = v0*v0 + v1*v1;
    #pragma unroll
    for (int o = 32; o; o >>= 1) { s += __shfl_xor(s, o); q += __shfl_xor(q, o); }
    __shared__ float ls[4], lq[4];
    int w = t >> 6;
    if ((t & 63) == 0) { ls[w] = s; lq[w] = q; }
    __syncthreads();
    s = ls[0]+ls[1]+ls[2]+ls[3];
    q = lq[0]+lq[1]+lq[2]+lq[3];
    float mean = s * (1.f/512.f);
    float var  = q * (1.f/512.f) - mean*mean;
    float inv  = rsqrtf(var + 1e-5f);
    float o0 = (v0-mean)*inv*gw[t]     + gb[t];
    float o1 = (v1-mean)*inv*gw[t+256] + gb[t+256];
    if (act == 2) { o0 = geluf_(o0); o1 = geluf_(o1); }
    if (f32out)  { f32out[(size_t)row*512 + t] = o0; f32out[(size_t)row*512 + t + 256] = o1; }
    if (bf16out) { bf16out[(size_t)row*512 + t] = f2bf(o0); bf16out[(size_t)row*512 + t + 256] = f2bf(o1); }
}

// =============== causal depthwise conv (K=4) + SiLU, bf16 in, f32 out ===============
__global__ __launch_bounds__(256) void conv_silu(
    const u16* __restrict__ xzb, const float* __restrict__ cw,
    const float* __restrict__ cb, float* __restrict__ uo)
{
    int idx = blockIdx.x*256 + threadIdx.x;
    int dq = idx & 255;
    int r  = idx >> 8;
    int b = r / LSEQ, l = r - b*LSEQ;
    int d0 = dq << 2;
    float4 w0 = *(const float4*)&cw[(d0+0)*4];
    float4 w1 = *(const float4*)&cw[(d0+1)*4];
    float4 w2 = *(const float4*)&cw[(d0+2)*4];
    float4 w3 = *(const float4*)&cw[(d0+3)*4];
    float4 acc = *(const float4*)&cb[d0];
    const float* wv0 = &w0.x; const float* wv1 = &w1.x;
    const float* wv2 = &w2.x; const float* wv3 = &w3.x;
    #pragma unroll
    for (int k = 0; k < KCONV; ++k) {
        int ls = l - (KCONV-1) + k;
        if (ls >= 0) {
            ushort4 v = *(const ushort4*)&xzb[((size_t)(b*LSEQ + ls))*2048 + d0];
            acc.x = fmaf(wv0[k], bf2f(v.x), acc.x);
            acc.y = fmaf(wv1[k], bf2f(v.y), acc.y);
            acc.z = fmaf(wv2[k], bf2f(v.z), acc.z);
            acc.w = fmaf(wv3[k], bf2f(v.w), acc.w);
        }
    }
    acc.x *= sigmoidf_(acc.x);
    acc.y *= sigmoidf_(acc.y);
    acc.z *= sigmoidf_(acc.z);
    acc.w *= sigmoidf_(acc.w);
    *(float4*)&uo[(size_t)r*DIN + d0] = acc;
}

// =============== single-pass fused selective scan (dt-proj + scan + gate) ===============
// grid (64 dg, 4 b), block 256 = 16 d x 16 n. Full L=1025 per block.
// 64-t chunks, double-buffered LDS, issue-early/write-late reg staging.
__global__ __launch_bounds__(256) void scan_full(
    const float* __restrict__ u,    const float* __restrict__ xdbl,
    const u16*   __restrict__ xzb,  const float* __restrict__ dtW,
    const float* __restrict__ dtb,  const float* __restrict__ A_log,
    const float* __restrict__ Dp,   u16* __restrict__ yb)
{
    const int dg = blockIdx.x, b = blockIdx.y;
    const int tid = threadIdx.x;
    const int n = tid & 15, dl = tid >> 4;
    const int d0 = dg*16, d = d0 + dl;
    const float Adn2 = -__expf(A_log[(size_t)d*DSTATE + n]) * 1.44269504f;
    const float Dd = Dp[d];

    __shared__ float sX[2][64][68];   // xdbl rows [buf][t][64(+pad)]
    __shared__ float sU[2][16][68];   // u transposed [buf][d][t]
    __shared__ float sZ[2][16][68];   // z transposed
    __shared__ float sDel[16][68];    // delta [d][t] (current chunk)
    __shared__ u16  sY[64][17];       // y staging [t][d]

    // dt_W column for this thread's d-col (tc = n) held in registers
    float rW[32];
    #pragma unroll
    for (int k = 0; k < 32; ++k) rW[k] = dtW[(size_t)k*DIN + d0 + n];
    const float db = dtb[d0 + n];

    const size_t base = (size_t)b * LSEQ;
    const int sr = tid >> 2;          // staging row 0..63
    const int sq = tid & 3;           // staging quad

    float4 rX[4]; float4 rU; ushort4 rZ;
    auto LOADG = [&](int c){
        size_t row = base + (size_t)c*64 + sr;
        #pragma unroll
        for (int j = 0; j < 4; ++j)
            rX[j] = *(const float4*)&xdbl[row*64 + sq*16 + j*4];
        rU = *(const float4*)&u[row*DIN + d0 + sq*4];
        rZ = *(const ushort4*)&xzb[row*2048 + DIN + d0 + sq*4];
    };
    auto WRITES = [&](int pb){
        #pragma unroll
        for (int j = 0; j < 4; ++j)
            *(float4*)&sX[pb][sr][sq*16 + j*4] = rX[j];
        sU[pb][sq*4+0][sr] = rU.x; sU[pb][sq*4+1][sr] = rU.y;
        sU[pb][sq*4+2][sr] = rU.z; sU[pb][sq*4+3][sr] = rU.w;
        sZ[pb][sq*4+0][sr] = bf2f(rZ.x); sZ[pb][sq*4+1][sr] = bf2f(rZ.y);
        sZ[pb][sq*4+2][sr] = bf2f(rZ.z); sZ[pb][sq*4+3][sr] = bf2f(rZ.w);
    };

    LOADG(0); WRITES(0);
    __syncthreads();
    float h = 0.f;
    for (int c = 0; c < 16; ++c) {
        const int pb = c & 1;
        if (c < 15) LOADG(c+1);            // issue next-chunk loads early
        // delta for chunk c: thread covers (t = sub*16 + dl, dcol = n)
        #pragma unroll
        for (int sub = 0; sub < 4; ++sub) {
            int t = sub*16 + dl;
            float acc = db;
            #pragma unroll
            for (int k = 0; k < 32; ++k) acc = fmaf(sX[pb][t][k], rW[k], acc);
            sDel[n][t] = softplusf_(acc);
        }
        __syncthreads();
        // recurrence: 4 sub-groups of 16 t
        #pragma unroll
        for (int sub = 0; sub < 4; ++sub) {
            float Bv[16], Cv[16];
            #pragma unroll
            for (int t = 0; t < 16; ++t) {
                Bv[t] = sX[pb][sub*16+t][DTRANK + n];
                Cv[t] = sX[pb][sub*16+t][DTRANK + DSTATE + n];
            }
            f32x4 vD[4], vU[4];
            #pragma unroll
            for (int q4 = 0; q4 < 4; ++q4) {
                vD[q4] = *(const f32x4*)&sDel[dl][sub*16 + q4*4];
                vU[q4] = *(const f32x4*)&sU[pb][dl][sub*16 + q4*4];
            }
            float py = 0.f;
            #pragma unroll
            for (int t = 0; t < 16; ++t) {
                float dv = vD[t>>2][t&3];
                float uv = vU[t>>2][t&3];
                h = fmaf(__builtin_exp2f(dv * Adn2), h, dv*uv*Bv[t]);
                float pr = red16(h * Cv[t]);
                py = (n == t) ? pr : py;
            }
            // thread (dl, n) finalizes y(t = sub*16+n, d = d0+dl)
            float uv_e = sU[pb][dl][sub*16 + n];
            float zv   = sZ[pb][dl][sub*16 + n];
            sY[sub*16 + n][dl] = f2bf((py + uv_e*Dd) * (zv * sigmoidf_(zv)));
        }
        __syncthreads();
        // coalesced y write + stage next chunk into LDS
        {
            ushort4 o;
            o.x = sY[sr][sq*4+0]; o.y = sY[sr][sq*4+1];
            o.z = sY[sr][sq*4+2]; o.w = sY[sr][sq*4+3];
            *(ushort4*)&yb[(base + (size_t)c*64 + sr)*DIN + d0 + sq*4] = o;
        }
        if (c < 15) WRITES((c+1) & 1);
        __syncthreads();
    }
    // tail row 1024
    {
        size_t row = base + 1024;
        float acc = dtb[d];
        #pragma unroll
        for (int k = 0; k < 32; ++k)
            acc = fmaf(xdbl[row*64 + k], dtW[(size_t)k*DIN + d], acc);
        float dv = softplusf_(acc);
        float uv = u[row*DIN + d];
        float zv = bf2f(xzb[row*2048 + DIN + d]);
        float Bv = xdbl[row*64 + DTRANK + n];
        float Cv = xdbl[row*64 + DTRANK + DSTATE + n];
        h = fmaf(__builtin_exp2f(dv * Adn2), h, dv*uv*Bv);
        float p = red16(h * Cv);
        if (n == 0)
            yb[row*DIN + d] = f2bf((p + uv*Dd) * (zv * sigmoidf_(zv)));
    }
}

// =============== softmax-pool ===============
__global__ __launch_bounds__(256) void softpool_seg(
    const float* __restrict__ a, const float* __restrict__ yh,
    float* __restrict__ pm, float* __restrict__ ps, float* __restrict__ pp)
{
    int b   = blockIdx.y;
    int seg = blockIdx.z;
    int jj = threadIdx.x & 63;
    int j  = blockIdx.x * 64 + jj;
    int li = threadIdx.x >> 6;
    int lbeg = seg * 64;
    int lend = min(lbeg + 64, LSEQ);
    float m = -3.0e38f, s = 0.f, p = 0.f;
    for (int l = lbeg + li; l < lend; l += 4) {
        size_t off = ((size_t)(b*LSEQ + l))*OUTD + j;
        float av = a[off], yv = yh[off];
        float mn = fmaxf(m, av);
        float sc = __expf(m - mn);
        float e  = __expf(av - mn);
        s = s*sc + e;
        p = p*sc + yv*e;
        m = mn;
    }
    __shared__ float sm[4][64], ss[4][64], sp[4][64];
    sm[li][jj] = m; ss[li][jj] = s; sp[li][jj] = p;
    __syncthreads();
    if (li == 0) {
        #pragma unroll
        for (int k2 = 1; k2 < 4; ++k2) {
            float m2 = sm[k2][jj], s2 = ss[k2][jj], p2 = sp[k2][jj];
            float M2 = fmaxf(m, m2);
            float c1 = __expf(m - M2), c2 = __expf(m2 - M2);
            s = s*c1 + s2*c2;
            p = p*c1 + p2*c2;
            m = M2;
        }
        int o = ((seg*B_ + b)*OUTD) + j;
        pm[o] = m; ps[o] = s; pp[o] = p;
    }
}

__global__ __launch_bounds__(256) void softpool_combine(
    const float* __restrict__ pm, const float* __restrict__ ps,
    const float* __restrict__ pp, float* __restrict__ pooled)
{
    int idx = blockIdx.x*256 + threadIdx.x;
    int b = idx >> 9, j = idx & 511;
    float m = -3.0e38f, s = 0.f, p = 0.f;
    #pragma unroll
    for (int seg = 0; seg < NSEG_SP; ++seg) {
        int o = ((seg*B_ + b)*OUTD) + j;
        float m2 = pm[o], s2 = ps[o], p2 = pp[o];
        float M2 = fmaxf(m, m2);
        float c1 = __expf(m - M2), c2 = __expf(m2 - M2);
        s = s*c1 + s2*c2;
        p = p*c1 + p2*c2;
        m = M2;
    }
    pooled[(size_t)b*OUTD + j] = p / s;
}

extern "C" void kernel_launch(void* const* d_in, const int* in_sizes, int n_in,
                              void* d_out, int out_size, void* d_ws, size_t ws_size,
                              hipStream_t stream) {
    const float* img     = (const float*)d_in[0];
    const float* patch_W = (const float*)d_in[1];
    const float* patch_b = (const float*)d_in[2];
    const float* pos_emb = (const float*)d_in[3];
    const float* cls_tok = (const float*)d_in[4];
    const float* ln_w    = (const float*)d_in[5];
    const float* ln_b    = (const float*)d_in[6];
    const float* in_W    = (const float*)d_in[7];
    const float* conv_w  = (const float*)d_in[8];
    const float* conv_b  = (const float*)d_in[9];
    const float* xproj_W = (const float*)d_in[10];
    const float* dt_W    = (const float*)d_in[11];
    const float* dt_b    = (const float*)d_in[12];
    const float* A_log   = (const float*)d_in[13];
    const float* Dp      = (const float*)d_in[14];
    const float* out_W   = (const float*)d_in[15];
    const float* sl1_W   = (const float*)d_in[16];
    const float* sl1_b   = (const float*)d_in[17];
    const float* sl1_lnw = (const float*)d_in[18];
    const float* sl1_lnb = (const float*)d_in[19];
    const float* sl2_W   = (const float*)d_in[20];
    const float* sl2_b   = (const float*)d_in[21];
    const float* sl2_lnw = (const float*)d_in[22];
    const float* sl2_lnb = (const float*)d_in[23];
    const float* lat_lnw = (const float*)d_in[24];
    const float* lat_lnb = (const float*)d_in[25];
    float* out = (float*)d_out;
    float* ws  = (float*)d_ws;

    // ---- f32 workspace (floats) ----
    float* x      = ws + 0;
    u16*   xz_bf  = (u16*)(ws + 2099200);
    float* yh     = ws + 6297600;
    float* t2     = ws + 8396800;
    float* u      = ws + 10496000;
    float* xdbl   = ws + 14694400;
    float* scratch= ws + 14956800;
    // ---- bf16 pool ----
    u16* ub      = (u16*)(ws + 19155200);
    u16* regA    = ub + 0;
    u16* regB    = ub + 4325376;
    u16* pWt     = ub + 6758400;
    u16* inWt    = ub + 7151616;
    u16* outWt   = ub + 9248768;
    u16* s1t     = ub + 10362880;
    u16* s2t     = ub + 10625024;

    float* a      = u;
    float* pooled = xdbl;
    float* spm    = xdbl + 8192;
    float* sps    = spm + 34816;
    float* spp    = sps + 34816;
    float* t1     = scratch;
    float* xprojP = scratch;

    // 0) prep
    prep_kernel<<<7040, 256, 0, stream>>>(img, patch_W, in_W, out_W, sl1_W, sl2_W,
                                          regA, pWt, inWt, outWt, s1t, s2t);

    // 1) patch GEMM + assemble
    gemm_mfma<2><<<dim3(512/128, 4096/64), 256, 0, stream>>>(
        regA, PDIM, pWt, scratch, DIM, 4096, DIM, PDIM, patch_b, nullptr, 0, nullptr);
    assemble_x<<<(MROWS*DIM)/256, 256, 0, stream>>>(scratch, cls_tok, pos_emb, x);

    // 2) mamba blocks
    for (int i = 0; i < NBLK; ++i) {
        ln_act<<<MROWS, 256, 0, stream>>>(x, ln_w + i*DIM, ln_b + i*DIM,
                                          nullptr, regB, 0);
        gemm_mfma<4><<<dim3(2048/128, 33), 256, 0, stream>>>(
            regB, DIM, inWt + (size_t)i*1048576, nullptr, 2048,
            MROWS, 2*DIN, DIM, nullptr, nullptr, 0, xz_bf);
        conv_silu<<<MROWS, 256, 0, stream>>>(
            xz_bf, conv_w + i*DIN*KCONV, conv_b + i*DIN, u);
        xproj_gemm<<<dim3(65, 4), 256, 0, stream>>>(
            u, xproj_W + (size_t)i*DIN*64, xprojP);
        xproj_reduce<<<1025, 256, 0, stream>>>(xprojP, xdbl);
        scan_full<<<dim3(64, 4), 256, 0, stream>>>(
            u, xdbl, xz_bf, dt_W + (size_t)i*DTRANK*DIN, dt_b + i*DIN,
            A_log + (size_t)i*DIN*DSTATE, Dp + i*DIN, regA);
        gemm_mfma<2><<<dim3(512/128, 65), 256, 0, stream>>>(
            regA, DIN, outWt + (size_t)i*524288, x, DIM,
            MROWS, DIM, DIN, nullptr, x, 0, (i == NBLK-1) ? regB : nullptr);
    }

    // 3) head
    gemm_mfma<2><<<dim3(512/128, 65), 256, 0, stream>>>(
        regB, DIM, s1t, t1, OUTD, MROWS, OUTD, DIM, sl1_b, nullptr, 0, nullptr);
    ln_act<<<MROWS, 256, 0, stream>>>(t1, sl1_lnw, sl1_lnb, yh, regA, 2);
    gemm_mfma<2><<<dim3(512/128, 65), 256, 0, stream>>>(
        regA, OUTD, s2t, t2, OUTD, MROWS, OUTD, OUTD, sl2_b, nullptr, 0, nullptr);
    ln_act<<<MROWS, 256, 0, stream>>>(t2, sl2_lnw, sl2_lnb, a, nullptr, 2);
    softpool_seg<<<dim3(OUTD/64, B_, NSEG_SP), 256, 0, stream>>>(a, yh, spm, sps, spp);
    softpool_combine<<<8, 256, 0, stream>>>(spm, sps, spp, pooled);
    ln_act<<<B_, 256, 0, stream>>>(pooled, lat_lnw, lat_lnb, out, nullptr, 0);
}